// Round 16
// baseline (781.831 us; speedup 1.0000x reference)
//
#include <hip/hip_runtime.h>
#include <math.h>

#define NN      50000
#define NNP     50048          // padded nodes = 391*128
#define NE      2400000
#define NHOPS   3
#define NG      2048
#define H       128
#define EMBD    64
#define NL      3
#define NMLP    2
#define NHEADS  4
#define NROWS   (NHOPS * NN)   // 150000
#define BINSH   9              // 512 rows per coarse bin
#define NBIN    293            // ceil(150016/512)
#define CAPB    12288          // per-bin region capacity
#define ABLK    1024           // binning blocks
#define DEPTH   32             // LDS circular buffer depth per bin
#define STG     6144           // fill2b per-half stage capacity
#define LSTR    136
#define AGSTR   136            // agg LDS row stride (2-way bank pattern = free)
#define SENT    0xFFFFFFFFu

typedef __bf16 bf16x8 __attribute__((ext_vector_type(8)));
typedef __bf16 bf16x4 __attribute__((ext_vector_type(4)));
typedef float  f32x4  __attribute__((ext_vector_type(4)));

__device__ __forceinline__ float silu_f(float v) { return v / (1.0f + expf(-v)); }

__device__ __forceinline__ f32x4 mm(bf16x8 a, bf16x8 b, f32x4 c) {
    return __builtin_amdgcn_mfma_f32_16x16x32_bf16(a, b, c, 0, 0, 0);
}

__device__ __forceinline__ float blo(unsigned v) { return __builtin_bit_cast(float, v << 16); }
__device__ __forceinline__ float bhi(unsigned v) { return __builtin_bit_cast(float, v & 0xffff0000u); }
__device__ __forceinline__ unsigned pk2(float a, float b) {
    unsigned short ua = __builtin_bit_cast(unsigned short, (__bf16)a);
    unsigned short ub = __builtin_bit_cast(unsigned short, (__bf16)b);
    return (unsigned)ua | ((unsigned)ub << 16);
}

// ---------------------------------------------------------------- fused weight pack + emb convert
__device__ __forceinline__ void packw_elem(
    const float* __restrict__ W, __bf16* __restrict__ out, int K, long idx)
{
    long per = (long)K * 128;
    long mat = idx / per, e = idx - mat * per;
    int j = (int)(e & 7), n16 = (int)((e >> 3) & 15), q = (int)((e >> 7) & 3),
        mt = (int)((e >> 9) & 7), kt = (int)(e >> 12);
    int k = kt * 32 + q * 8 + j, n = mt * 16 + n16;
    out[idx] = (__bf16)W[mat * per + (long)k * 128 + n];
}

__global__ __launch_bounds__(256) void k_packall(
    const float* __restrict__ projW, __bf16* __restrict__ pproj,
    const float* __restrict__ sInW,  __bf16* __restrict__ pin,
    const float* __restrict__ sSkW,  __bf16* __restrict__ psk,
    const float* __restrict__ mW1,   __bf16* __restrict__ pw1,
    const float* __restrict__ mW2,   __bf16* __restrict__ pw2,
    const float* __restrict__ Ea, const float* __restrict__ Eh,
    const float* __restrict__ Ed, const float* __restrict__ Ey,
    __bf16* __restrict__ embb)
{
    long tid = (long)blockIdx.x * 256 + threadIdx.x;
    if (tid < 32768) { packw_elem(projW, pproj, 256, tid); return; }
    tid -= 32768;
    if (tid < 196608) { packw_elem(sInW, pin, 512, tid); return; }
    tid -= 196608;
    if (tid < 196608) { packw_elem(sSkW, psk, 512, tid); return; }
    tid -= 196608;
    if (tid < 98304) { packw_elem(mW1, pw1, 128, tid); return; }
    tid -= 98304;
    if (tid < 98304) { packw_elem(mW2, pw2, 128, tid); return; }
    tid -= 98304;
    if (tid < 8000) {
        int t = (int)tid;
        float v;
        if (t < 6400) v = Ea[t];
        else if (t < 6976) v = Eh[t - 6400];
        else if (t < 7488) v = Ed[t - 6976];
        else v = Ey[t - 7488];
        embb[t] = (__bf16)v;
    }
}

// ---------------------------------------------------------------- K0: embed + project + silu (MFMA)
__global__ __launch_bounds__(256) void k_embed_m(
    const int* __restrict__ atom, const int* __restrict__ hc,
    const int* __restrict__ deg,  const int* __restrict__ hyb,
    const __bf16* __restrict__ emb, const __bf16* __restrict__ pw,
    const float* __restrict__ pb, __bf16* __restrict__ x)
{
    const int lane = threadIdx.x & 63, wid = threadIdx.x >> 6;
    const int q = lane >> 4, l16 = lane & 15;
    const int nb = blockIdx.x * 128 + wid * 32;
    int ia[2][4];
#pragma unroll
    for (int nt = 0; nt < 2; ++nt) {
        int n = nb + nt * 16 + l16;
        if (n >= NN) n = NN - 1;
        ia[nt][0] = atom[n]; ia[nt][1] = hc[n]; ia[nt][2] = deg[n]; ia[nt][3] = hyb[n];
    }
    f32x4 acc[2][8];
#pragma unroll
    for (int nt = 0; nt < 2; ++nt)
#pragma unroll
        for (int mt = 0; mt < 8; ++mt) acc[nt][mt] = (f32x4)(0.f);
    const int tb[4] = {0, 6400, 6976, 7488};
    for (int kt = 0; kt < 8; ++kt) {
        int t = kt >> 1;
        int koff = (kt & 1) * 32 + q * 8;
        bf16x8 bfrag[2];
#pragma unroll
        for (int nt = 0; nt < 2; ++nt)
            bfrag[nt] = *(const bf16x8*)(emb + tb[t] + (long)ia[nt][t] * 64 + koff);
        const __bf16* ap = pw + (long)kt * 4096 + lane * 8;
#pragma unroll
        for (int mt = 0; mt < 8; ++mt) {
            bf16x8 a = *(const bf16x8*)(ap + mt * 512);
            acc[0][mt] = mm(a, bfrag[0], acc[0][mt]);
            acc[1][mt] = mm(a, bfrag[1], acc[1][mt]);
        }
    }
#pragma unroll
    for (int nt = 0; nt < 2; ++nt) {
        long node = nb + nt * 16 + l16;
#pragma unroll
        for (int mt = 0; mt < 8; ++mt) {
            int ch = mt * 16 + q * 4;
            float4 bb = *(const float4*)(pb + ch);
            bf16x4 o;
            o[0] = (__bf16)silu_f(acc[nt][mt][0] + bb.x);
            o[1] = (__bf16)silu_f(acc[nt][mt][1] + bb.y);
            o[2] = (__bf16)silu_f(acc[nt][mt][2] + bb.z);
            o[3] = (__bf16)silu_f(acc[nt][mt][3] + bb.w);
            *(bf16x4*)(x + node * 128 + ch) = o;
        }
    }
}

// ---------------------------------------------------------------- CSR pass A: LDS write-combined binning
__global__ __launch_bounds__(256) void k_binA(
    const int* __restrict__ target, const int* __restrict__ src,
    int* __restrict__ gbincur, int* __restrict__ brealc,
    unsigned int* __restrict__ binreg)
{
    __shared__ unsigned int buf[NBIN][DEPTH];
    __shared__ int cnt[NBIN];
    __shared__ int flushed[NBIN];
    const int tid = threadIdx.x;
    for (int i = tid; i < NBIN; i += 256) { cnt[i] = 0; flushed[i] = 0; }
    __syncthreads();
    const int per = (NE + ABLK - 1) / ABLK;   // 2344
    const int e0 = blockIdx.x * per;
    const int e1 = (e0 + per < NE) ? e0 + per : NE;
    for (int base = e0; base < e1; base += 256) {
        int e = base + tid;
        if (e < e1) {
            int s = src[e];
            if (s >= 2 * NN) s -= 2 * NN; else if (s >= NN) s -= NN;
            int t = target[e];
            int bin = t >> BINSH;
            unsigned val = (unsigned)s | ((unsigned)(t & ((1 << BINSH) - 1)) << 16);
            int slot = atomicAdd(&cnt[bin], 1);
            buf[bin][slot & (DEPTH - 1)] = val;
        }
        __syncthreads();
        for (int b = tid; b < NBIN; b += 256) {
            while (cnt[b] - flushed[b] >= 16) {
                int pos = atomicAdd(&gbincur[b], 16);
                if (pos + 16 <= CAPB) {
                    uint4* d4 = (uint4*)(binreg + (long)b * CAPB + pos);
                    const uint4* s4 = (const uint4*)&buf[b][flushed[b] & (DEPTH - 1)];
                    d4[0] = s4[0]; d4[1] = s4[1]; d4[2] = s4[2]; d4[3] = s4[3];
                }
                flushed[b] += 16;
            }
        }
        __syncthreads();
    }
    for (int b = tid; b < NBIN; b += 256) {
        int lvl = cnt[b] - flushed[b];
        if (cnt[b] > 0) atomicAdd(&brealc[b], cnt[b]);
        if (lvl > 0) {
            int pad = (lvl + 3) & ~3;
            int pos = atomicAdd(&gbincur[b], pad);
            for (int i = 0; i < pad; i += 4) {
                uint4 v;
                v.x = (i + 0 < lvl) ? buf[b][(flushed[b] + i + 0) & (DEPTH - 1)] : SENT;
                v.y = (i + 1 < lvl) ? buf[b][(flushed[b] + i + 1) & (DEPTH - 1)] : SENT;
                v.z = (i + 2 < lvl) ? buf[b][(flushed[b] + i + 2) & (DEPTH - 1)] : SENT;
                v.w = (i + 3 < lvl) ? buf[b][(flushed[b] + i + 3) & (DEPTH - 1)] : SENT;
                if (pos + i + 4 <= CAPB)
                    *(uint4*)(binreg + (long)b * CAPB + pos + i) = v;
            }
        }
    }
}

// ---------------------------------------------------------------- CSR pass B: per-HALF-bin LDS finalize
__global__ __launch_bounds__(512) void k_fill2b(
    const unsigned int* __restrict__ binreg, const int* __restrict__ gbincur,
    const int* __restrict__ brealc, int* __restrict__ csr_start,
    unsigned short* __restrict__ esrc)
{
    __shared__ unsigned int stage[STG];
    __shared__ int pc[512], rcnt[256], scn[256], cur[256];
    __shared__ int nstage;
    const int blk = blockIdx.x;
    const int b = blk >> 1, half = blk & 1;
    const int tid = threadIdx.x;
    int pv = (tid < NBIN) ? brealc[tid] : 0;
    if (pv < 0) pv = 0;
    pc[tid] = pv;
    if (tid == 0) nstage = 0;
    if (tid < 256) rcnt[tid] = 0;
    __syncthreads();
    for (int off = 1; off < 512; off <<= 1) {
        int t = (tid >= off) ? pc[tid - off] : 0;
        __syncthreads();
        pc[tid] += t;
        __syncthreads();
    }
    const int bbase = (b == 0) ? 0 : pc[b - 1];
    const int breal = pc[b] - bbase;
    int total = gbincur[b];
    if (total > CAPB) total = CAPB;
    if (total < 0) total = 0;
    const unsigned int* seg = binreg + (long)b * CAPB;
    for (int i = tid; i < total; i += 512) {
        unsigned pk = seg[i];
        if (pk == SENT) continue;
        int tl = (pk >> 16) & 511;
        if ((tl >> 8) == half) {
            int p = atomicAdd(&nstage, 1);
            if (p < STG) stage[p] = pk;
            atomicAdd(&rcnt[tl & 255], 1);
        }
    }
    __syncthreads();
    int own = nstage; if (own > STG) own = STG;
    const int base0 = bbase + (half ? (breal - own) : 0);
    if (tid < 256) scn[tid] = rcnt[tid];
    __syncthreads();
    for (int off = 1; off < 256; off <<= 1) {
        int t = (tid >= off && tid < 256) ? scn[tid - off] : 0;
        __syncthreads();
        if (tid < 256) scn[tid] += t;
        __syncthreads();
    }
    if (tid < 256) {
        int v = rcnt[tid];
        int rb = base0 + scn[tid] - v;
        cur[tid] = rb;
        int row = b * 512 + half * 256 + tid;
        if (row <= NROWS) csr_start[row] = rb;
    }
    __syncthreads();
    for (int i = tid; i < own; i += 512) {
        unsigned pk = stage[i];
        int pos = atomicAdd(&cur[(pk >> 16) & 255], 1);
        if (pos >= 0 && pos < NE) esrc[pos] = (unsigned short)(pk & 0xffffu);
    }
}

// ---------------------------------------------------------------- K2: FUSED gather + layer
// Block = 128 threads (2 waves), 16 nodes. Each block gathers its 48 agg rows
// (3 hops x 16 nodes) into LDS, then shell+2xMLP with channel-half waves.
// Gather-phase blocks saturate memory pipes while MFMA-phase blocks use matrix
// pipes -> the two bottlenecks co-schedule instead of serializing.
__global__ __launch_bounds__(128) void k_layer_g(
    const unsigned short* __restrict__ esrc, const int* __restrict__ csr_start,
    const __bf16* __restrict__ x,
    const __bf16* __restrict__ pwin, const float* __restrict__ bin,
    const __bf16* __restrict__ pwsk, const float* __restrict__ bsk,
    const __bf16* __restrict__ pw1a, const float* __restrict__ b1a,
    const __bf16* __restrict__ pw2a, const float* __restrict__ b2a,
    const __bf16* __restrict__ pw1b, const float* __restrict__ b1b,
    const __bf16* __restrict__ pw2b, const float* __restrict__ b2b,
    __bf16* __restrict__ xout)
{
    __shared__ __bf16 AG[48 * AGSTR];        // hop rows; rows 0..15 reused as act buffer
    const int lane = threadIdx.x & 63, half = threadIdx.x >> 6;
    const int q = lane >> 4, l16 = lane & 15;
    const int nb = blockIdx.x * 16;
    const int mtoff = half * 4 * 512;
    const int chb = half * 64;
    const int la = lane * 8;
    const long r0 = (long)(nb + l16) * 128;
    const uint4* x8 = (const uint4*)x;

    // ================= gather phase: 24 rows per wave, 4 rows per pass =================
    {
        const int l4 = lane & 15, qw = lane >> 4;
        const int sb = qw << 4;
#pragma unroll
        for (int p = 0; p < 6; ++p) {
            int ridx = half * 24 + p * 4 + qw;          // 0..47
            int hop = ridx >> 4, nloc = ridx & 15;
            int node = nb + nloc;
            int e0 = 0, e1 = 0;
            if (node < NN) {
                int grow = hop * NN + node;
                e0 = csr_start[grow]; e1 = csr_start[grow + 1];
                if ((unsigned)e0 > NE || (unsigned)e1 > NE || e1 < e0) { e0 = 0; e1 = 0; }
            }
            int nch = (e1 - e0 + 15) >> 4;
            int n0 = __shfl(nch, sb - sb + (half ? 32 : 0) + 0, 64);  // group leaders 0,16,32,48
            n0 = __shfl(nch, 0, 64);
            int n1 = __shfl(nch, 16, 64);
            int n2 = __shfl(nch, 32, 64);
            int n3 = __shfl(nch, 48, 64);
            int nmax = max(max(n0, n1), max(n2, n3));
            float a0 = 0.f, a1 = 0.f, a2 = 0.f, a3 = 0.f, a4 = 0.f, a5 = 0.f, a6 = 0.f, a7 = 0.f;
            for (int c = 0; c < nmax; ++c) {
                int base = e0 + c * 16;
                int rem = e1 - base;
                int pre = (l4 < rem) ? (int)esrc[base + l4] : 0;
                int m = rem < 16 ? (rem < 0 ? 0 : rem) : 16;
                int j = 0;
                for (; j + 3 < m; j += 4) {
                    int sA = __shfl(pre, sb + j, 64);
                    int sB = __shfl(pre, sb + j + 1, 64);
                    int sC = __shfl(pre, sb + j + 2, 64);
                    int sD = __shfl(pre, sb + j + 3, 64);
                    uint4 v0 = x8[(long)sA * 16 + l4];
                    uint4 v1 = x8[(long)sB * 16 + l4];
                    uint4 v2 = x8[(long)sC * 16 + l4];
                    uint4 v3 = x8[(long)sD * 16 + l4];
                    a0 += blo(v0.x) + blo(v1.x) + blo(v2.x) + blo(v3.x);
                    a1 += bhi(v0.x) + bhi(v1.x) + bhi(v2.x) + bhi(v3.x);
                    a2 += blo(v0.y) + blo(v1.y) + blo(v2.y) + blo(v3.y);
                    a3 += bhi(v0.y) + bhi(v1.y) + bhi(v2.y) + bhi(v3.y);
                    a4 += blo(v0.z) + blo(v1.z) + blo(v2.z) + blo(v3.z);
                    a5 += bhi(v0.z) + bhi(v1.z) + bhi(v2.z) + bhi(v3.z);
                    a6 += blo(v0.w) + blo(v1.w) + blo(v2.w) + blo(v3.w);
                    a7 += bhi(v0.w) + bhi(v1.w) + bhi(v2.w) + bhi(v3.w);
                }
                for (; j < m; ++j) {
                    int sA = __shfl(pre, sb + j, 64);
                    uint4 v0 = x8[(long)sA * 16 + l4];
                    a0 += blo(v0.x); a1 += bhi(v0.x); a2 += blo(v0.y); a3 += bhi(v0.y);
                    a4 += blo(v0.z); a5 += bhi(v0.z); a6 += blo(v0.w); a7 += bhi(v0.w);
                }
            }
            uint4 o;
            o.x = pk2(a0, a1); o.y = pk2(a2, a3); o.z = pk2(a4, a5); o.w = pk2(a6, a7);
            *(uint4*)(AG + ridx * AGSTR + l4 * 8) = o;
        }
    }
    __syncthreads();   // all 48 agg rows staged

    // ================= shell phase: K=512; kt<4 from global x, kt>=4 from AG =================
    bf16x8 ring[4];
#pragma unroll
    for (int k = 0; k < 4; ++k)
        ring[k] = *(const bf16x8*)(x + k * 32 + q * 8 + r0);
    f32x4 aci[4], acs[4];
#pragma unroll
    for (int mt = 0; mt < 4; ++mt) { aci[mt] = (f32x4)(0.f); acs[mt] = (f32x4)(0.f); }
#pragma unroll
    for (int kt = 0; kt < 16; ++kt) {
        bf16x8 b0;
        if (kt < 4) b0 = ring[kt];
        else {
            int hop = (kt >> 2) - 1;
            b0 = *(const bf16x8*)(AG + (hop * 16 + l16) * AGSTR + (kt & 3) * 32 + q * 8);
        }
        const __bf16* aip = pwin + (long)kt * 4096 + mtoff + la;
        const __bf16* asp = pwsk + (long)kt * 4096 + mtoff + la;
#pragma unroll
        for (int mt = 0; mt < 4; ++mt) {
            aci[mt] = mm(*(const bf16x8*)(aip + mt * 512), b0, aci[mt]);
            acs[mt] = mm(*(const bf16x8*)(asp + mt * 512), b0, acs[mt]);
        }
    }
    bf16x4 gk[4];
    bf16x4 hs[4];
    __syncthreads();   // all AG reads done before act-area overwrite
#pragma unroll
    for (int mt = 0; mt < 4; ++mt) {
        int ch = chb + mt * 16 + q * 4;
        float4 bi = *(const float4*)(bin + ch);
        float4 bs = *(const float4*)(bsk + ch);
        bf16x4 oh, og;
        oh[0] = (__bf16)silu_f(aci[mt][0] + bi.x);
        oh[1] = (__bf16)silu_f(aci[mt][1] + bi.y);
        oh[2] = (__bf16)silu_f(aci[mt][2] + bi.z);
        oh[3] = (__bf16)silu_f(aci[mt][3] + bi.w);
        og[0] = (__bf16)(acs[mt][0] + bs.x);
        og[1] = (__bf16)(acs[mt][1] + bs.y);
        og[2] = (__bf16)(acs[mt][2] + bs.z);
        og[3] = (__bf16)(acs[mt][3] + bs.w);
        hs[mt] = oh; gk[mt] = og;
        *(bf16x4*)(AG + l16 * AGSTR + ch) = oh;     // act buffer = AG rows 0..15
    }
    __syncthreads();

    f32x4 acc[4];
    bf16x4 skipreg[4];
    __bf16* L = AG;    // act buffer alias

    // ---- p0: t1 = silu(h @ W1a + b1a) -> LDS ----
#pragma unroll
    for (int mt = 0; mt < 4; ++mt) acc[mt] = (f32x4)(0.f);
#pragma unroll
    for (int kt = 0; kt < 4; ++kt) {
        int koff = kt * 32 + q * 8;
        bf16x8 f0 = *(const bf16x8*)(L + l16 * AGSTR + koff);
        const __bf16* ap = pw1a + (long)kt * 4096 + mtoff + la;
#pragma unroll
        for (int mt = 0; mt < 4; ++mt)
            acc[mt] = mm(*(const bf16x8*)(ap + mt * 512), f0, acc[mt]);
    }
    __syncthreads();
#pragma unroll
    for (int mt = 0; mt < 4; ++mt) {
        int ch = chb + mt * 16 + q * 4;
        float4 bb = *(const float4*)(b1a + ch);
        bf16x4 o;
        o[0] = (__bf16)silu_f(acc[mt][0] + bb.x);
        o[1] = (__bf16)silu_f(acc[mt][1] + bb.y);
        o[2] = (__bf16)silu_f(acc[mt][2] + bb.z);
        o[3] = (__bf16)silu_f(acc[mt][3] + bb.w);
        *(bf16x4*)(L + l16 * AGSTR + ch) = o;
    }
    __syncthreads();

    // ---- p1: h2 = t1 @ W2a + b2a + h -> LDS + skipreg ----
#pragma unroll
    for (int mt = 0; mt < 4; ++mt) acc[mt] = (f32x4)(0.f);
#pragma unroll
    for (int kt = 0; kt < 4; ++kt) {
        int koff = kt * 32 + q * 8;
        bf16x8 f0 = *(const bf16x8*)(L + l16 * AGSTR + koff);
        const __bf16* ap = pw2a + (long)kt * 4096 + mtoff + la;
#pragma unroll
        for (int mt = 0; mt < 4; ++mt)
            acc[mt] = mm(*(const bf16x8*)(ap + mt * 512), f0, acc[mt]);
    }
    __syncthreads();
#pragma unroll
    for (int mt = 0; mt < 4; ++mt) {
        int ch = chb + mt * 16 + q * 4;
        float4 bb = *(const float4*)(b2a + ch);
        bf16x4 sk = hs[mt];
        bf16x4 o;
        o[0] = (__bf16)(acc[mt][0] + bb.x + (float)sk[0]);
        o[1] = (__bf16)(acc[mt][1] + bb.y + (float)sk[1]);
        o[2] = (__bf16)(acc[mt][2] + bb.z + (float)sk[2]);
        o[3] = (__bf16)(acc[mt][3] + bb.w + (float)sk[3]);
        skipreg[mt] = o;
        *(bf16x4*)(L + l16 * AGSTR + ch) = o;
    }
    __syncthreads();

    // ---- p2: t2 = silu(h2 @ W1b + b1b) -> LDS ----
#pragma unroll
    for (int mt = 0; mt < 4; ++mt) acc[mt] = (f32x4)(0.f);
#pragma unroll
    for (int kt = 0; kt < 4; ++kt) {
        int koff = kt * 32 + q * 8;
        bf16x8 f0 = *(const bf16x8*)(L + l16 * AGSTR + koff);
        const __bf16* ap = pw1b + (long)kt * 4096 + mtoff + la;
#pragma unroll
        for (int mt = 0; mt < 4; ++mt)
            acc[mt] = mm(*(const bf16x8*)(ap + mt * 512), f0, acc[mt]);
    }
    __syncthreads();
#pragma unroll
    for (int mt = 0; mt < 4; ++mt) {
        int ch = chb + mt * 16 + q * 4;
        float4 bb = *(const float4*)(b1b + ch);
        bf16x4 o;
        o[0] = (__bf16)silu_f(acc[mt][0] + bb.x);
        o[1] = (__bf16)silu_f(acc[mt][1] + bb.y);
        o[2] = (__bf16)silu_f(acc[mt][2] + bb.z);
        o[3] = (__bf16)silu_f(acc[mt][3] + bb.w);
        *(bf16x4*)(L + l16 * AGSTR + ch) = o;
    }
    __syncthreads();

    // ---- p3: x = t2 @ W2b + b2b + h2 + gskip -> global ----
#pragma unroll
    for (int mt = 0; mt < 4; ++mt) acc[mt] = (f32x4)(0.f);
#pragma unroll
    for (int kt = 0; kt < 4; ++kt) {
        int koff = kt * 32 + q * 8;
        bf16x8 f0 = *(const bf16x8*)(L + l16 * AGSTR + koff);
        const __bf16* ap = pw2b + (long)kt * 4096 + mtoff + la;
#pragma unroll
        for (int mt = 0; mt < 4; ++mt)
            acc[mt] = mm(*(const bf16x8*)(ap + mt * 512), f0, acc[mt]);
    }
    long node = nb + l16;
#pragma unroll
    for (int mt = 0; mt < 4; ++mt) {
        int ch = chb + mt * 16 + q * 4;
        float4 bb = *(const float4*)(b2b + ch);
        bf16x4 sk = skipreg[mt];
        bf16x4 g = gk[mt];
        bf16x4 o;
        o[0] = (__bf16)(acc[mt][0] + bb.x + (float)sk[0] + (float)g[0]);
        o[1] = (__bf16)(acc[mt][1] + bb.y + (float)sk[1] + (float)g[1]);
        o[2] = (__bf16)(acc[mt][2] + bb.z + (float)sk[2] + (float)g[2]);
        o[3] = (__bf16)(acc[mt][3] + bb.w + (float)sk[3] + (float)g[3]);
        *(bf16x4*)(xout + node * 128 + ch) = o;
    }
}

// ---------------------------------------------------------------- K4: attention scores
__global__ __launch_bounds__(256) void k_scores(
    const __bf16* __restrict__ x, const float* __restrict__ aw,
    const float* __restrict__ ab, const float* __restrict__ temp,
    float* __restrict__ scores)
{
    int wave = threadIdx.x >> 6, lane = threadIdx.x & 63;
    int n = blockIdx.x * 4 + wave;
    if (n >= NN) return;
    float x0 = (float)x[(long)n * H + lane];
    float x1 = (float)x[(long)n * H + 64 + lane];
    float T = temp[0];
#pragma unroll
    for (int hh = 0; hh < NHEADS; ++hh) {
        float p = x0 * aw[hh * H + lane] + x1 * aw[hh * H + 64 + lane];
#pragma unroll
        for (int off = 32; off >= 1; off >>= 1) p += __shfl_xor(p, off, 64);
        if (lane == 0) scores[n * NHEADS + hh] = (p + ab[hh]) / T;
    }
}

// ---------------------------------------------------------------- K5: graph offsets
__global__ __launch_bounds__(256) void k_offsets(
    const int* __restrict__ batch, int* __restrict__ gstart)
{
    int n = blockIdx.x * 256 + threadIdx.x;
    if (n >= NN) return;
    int b = batch[n];
    int bp = (n == 0) ? -1 : batch[n - 1];
    for (int g = bp + 1; g <= b; ++g) gstart[g] = n;
    if (n == NN - 1) for (int g = b + 1; g <= NG; ++g) gstart[g] = NN;
}

// ---------------------------------------------------------------- K6: softmax pool
__global__ __launch_bounds__(64) void k_pool(
    const __bf16* __restrict__ x, const float* __restrict__ scores,
    const int* __restrict__ gstart, float* __restrict__ pooled)
{
    int g = blockIdx.x, lane = threadIdx.x;
    int s0 = gstart[g], s1 = gstart[g + 1];
    float m0 = -INFINITY, m1 = -INFINITY, m2 = -INFINITY, m3 = -INFINITY;
    for (int n = s0 + lane; n < s1; n += 64) {
        m0 = fmaxf(m0, scores[n * 4 + 0]); m1 = fmaxf(m1, scores[n * 4 + 1]);
        m2 = fmaxf(m2, scores[n * 4 + 2]); m3 = fmaxf(m3, scores[n * 4 + 3]);
    }
#pragma unroll
    for (int off = 32; off >= 1; off >>= 1) {
        m0 = fmaxf(m0, __shfl_xor(m0, off, 64)); m1 = fmaxf(m1, __shfl_xor(m1, off, 64));
        m2 = fmaxf(m2, __shfl_xor(m2, off, 64)); m3 = fmaxf(m3, __shfl_xor(m3, off, 64));
    }
    float d0 = 0.f, d1 = 0.f, d2 = 0.f, d3 = 0.f;
    for (int n = s0 + lane; n < s1; n += 64) {
        d0 += expf(scores[n * 4 + 0] - m0); d1 += expf(scores[n * 4 + 1] - m1);
        d2 += expf(scores[n * 4 + 2] - m2); d3 += expf(scores[n * 4 + 3] - m3);
    }
#pragma unroll
    for (int off = 32; off >= 1; off >>= 1) {
        d0 += __shfl_xor(d0, off, 64); d1 += __shfl_xor(d1, off, 64);
        d2 += __shfl_xor(d2, off, 64); d3 += __shfl_xor(d3, off, 64);
    }
    float i0 = d0 > 0.f ? 1.f / d0 : 0.f;
    float i1 = d1 > 0.f ? 1.f / d1 : 0.f;
    float i2 = d2 > 0.f ? 1.f / d2 : 0.f;
    float i3 = d3 > 0.f ? 1.f / d3 : 0.f;
    float a0 = 0.f, a1 = 0.f;
    for (int n = s0; n < s1; ++n) {
        float wb = expf(scores[n * 4 + 0] - m0) * i0 + expf(scores[n * 4 + 1] - m1) * i1
                 + expf(scores[n * 4 + 2] - m2) * i2 + expf(scores[n * 4 + 3] - m3) * i3;
        wb *= 0.25f;
        a0 += wb * (float)x[(long)n * H + lane];
        a1 += wb * (float)x[(long)n * H + 64 + lane];
    }
    pooled[g * H + lane] = a0;
    pooled[g * H + 64 + lane] = a1;
}

// ---------------------------------------------------------------- K7: FFN readout
__global__ __launch_bounds__(128) void k_ffn(
    const float* __restrict__ pooled,
    const float* __restrict__ W1, const float* __restrict__ B1,
    const float* __restrict__ W2, const float* __restrict__ B2,
    const float* __restrict__ W3, const float* __restrict__ B3,
    float* __restrict__ out)
{
    __shared__ float p[H], t1[H], t2[H], red[H];
    int g = blockIdx.x, c = threadIdx.x;
    p[c] = pooled[g * H + c];
    __syncthreads();
    float acc = 0.f;
    for (int k = 0; k < H; ++k) acc += p[k] * W1[k * H + c];
    t1[c] = silu_f(acc + B1[c]);
    __syncthreads();
    acc = 0.f;
    for (int k = 0; k < H; ++k) acc += t1[k] * W2[k * H + c];
    t2[c] = silu_f(acc + B2[c]);
    __syncthreads();
    red[c] = t2[c] * W3[c];
    __syncthreads();
    for (int off = 64; off >= 1; off >>= 1) {
        if (c < off) red[c] += red[c + off];
        __syncthreads();
    }
    if (c == 0) out[g] = red[0] + B3[0];
}

// ---------------------------------------------------------------- launch
extern "C" void kernel_launch(void* const* d_in, const int* in_sizes, int n_in,
                              void* d_out, int out_size, void* d_ws, size_t ws_size,
                              hipStream_t stream)
{
    const int*   atom   = (const int*)d_in[0];
    const int*   hc     = (const int*)d_in[1];
    const int*   deg    = (const int*)d_in[2];
    const int*   hyb    = (const int*)d_in[3];
    const int*   target = (const int*)d_in[4];
    const int*   src    = (const int*)d_in[5];
    const int*   batch  = (const int*)d_in[6];
    const float* Ea     = (const float*)d_in[7];
    const float* Eh     = (const float*)d_in[8];
    const float* Ed     = (const float*)d_in[9];
    const float* Ey     = (const float*)d_in[10];
    const float* projW  = (const float*)d_in[11];
    const float* projB  = (const float*)d_in[12];
    const float* sInW   = (const float*)d_in[13];
    const float* sInB   = (const float*)d_in[14];
    const float* mW1    = (const float*)d_in[15];
    const float* mB1    = (const float*)d_in[16];
    const float* mW2    = (const float*)d_in[17];
    const float* mB2    = (const float*)d_in[18];
    const float* sSkW   = (const float*)d_in[19];
    const float* sSkB   = (const float*)d_in[20];
    const float* attnW  = (const float*)d_in[21];
    const float* attnB  = (const float*)d_in[22];
    const float* temp   = (const float*)d_in[23];
    const float* fW1    = (const float*)d_in[24];
    const float* fB1    = (const float*)d_in[25];
    const float* fW2    = (const float*)d_in[26];
    const float* fB2    = (const float*)d_in[27];
    const float* fW3    = (const float*)d_in[28];
    const float* fB3    = (const float*)d_in[29];
    float* out = (float*)d_out;

    char* w = (char*)d_ws;
    auto take = [&](size_t bytes) { void* p = (void*)w; w += (bytes + 255) & ~(size_t)255; return p; };
    __bf16* x      = (__bf16*)take(2L * NNP * H);
    __bf16* xnew   = (__bf16*)take(2L * NNP * H);
    __bf16* pproj  = (__bf16*)take(2L * 256 * H);
    __bf16* pin    = (__bf16*)take(2L * 3 * 512 * H);
    __bf16* psk    = (__bf16*)take(2L * 3 * 512 * H);
    __bf16* pw1    = (__bf16*)take(2L * 6 * 128 * H);
    __bf16* pw2    = (__bf16*)take(2L * 6 * 128 * H);
    __bf16* embb   = (__bf16*)take(2L * 8000);
    float*  scores = (float*)take(4L * NN * NHEADS);
    float*  pooled = (float*)take(4L * NG * H);
    int*    gstart = (int*)take(4L * (NG + 1));
    int*    csr_start = (int*)take(4L * (NROWS + 1));
    unsigned int*   binreg = (unsigned int*)take(4L * NBIN * CAPB);   // 14.4 MB
    unsigned short* esrc   = (unsigned short*)take(2L * NE);
    int*    gbincur = (int*)take(4L * 2 * NBIN);
    int*    brealc  = gbincur + NBIN;

    // ---- fused weight pack + emb convert (weights restored each call) ----
    k_packall<<<(630592 + 255) / 256, 256, 0, stream>>>(
        projW, pproj, sInW, pin, sSkW, psk, mW1, pw1, mW2, pw2,
        Ea, Eh, Ed, Ey, embb);

    // ---- CSR build: write-combined binning -> per-half-bin finalize ----
    hipMemsetAsync(gbincur, 0, sizeof(int) * 2 * NBIN, stream);
    k_binA<<<ABLK, 256, 0, stream>>>(target, src, gbincur, brealc, binreg);
    k_fill2b<<<2 * NBIN, 512, 0, stream>>>(binreg, gbincur, brealc, csr_start, esrc);

    k_embed_m<<<NNP / 128, 256, 0, stream>>>(atom, hc, deg, hyb, embb, pproj, projB, x);
    k_offsets<<<(NN + 255) / 256, 256, 0, stream>>>(batch, gstart);

    __bf16* xa = x;
    __bf16* xb = xnew;
    for (int l = 0; l < NL; ++l) {
        k_layer_g<<<NNP / 16, 128, 0, stream>>>(esrc, csr_start, xa,
            pin + (long)l * 512 * H, sInB + l * H,
            psk + (long)l * 512 * H, sSkB + l * H,
            pw1 + (long)(l * NMLP + 0) * 128 * H, mB1 + (long)(l * NMLP + 0) * H,
            pw2 + (long)(l * NMLP + 0) * 128 * H, mB2 + (long)(l * NMLP + 0) * H,
            pw1 + (long)(l * NMLP + 1) * 128 * H, mB1 + (long)(l * NMLP + 1) * H,
            pw2 + (long)(l * NMLP + 1) * 128 * H, mB2 + (long)(l * NMLP + 1) * H,
            xb);
        __bf16* t = xa; xa = xb; xb = t;
    }

    k_scores<<<NN / 4, 256, 0, stream>>>(xa, attnW, attnB, temp, scores);
    k_pool<<<NG, 64, 0, stream>>>(xa, scores, gstart, pooled);
    k_ffn<<<NG, 128, 0, stream>>>(pooled, fW1, fB1, fW2, fB2, fW3, fB3, out);
}

// Round 17
// 657.763 us; speedup vs baseline: 1.1886x; 1.1886x over previous
//
#include <hip/hip_runtime.h>
#include <math.h>

#define NN      50000
#define NNP     50048          // padded nodes = 391*128
#define NE      2400000
#define NHOPS   3
#define NG      2048
#define H       128
#define EMBD    64
#define NL      3
#define NMLP    2
#define NHEADS  4
#define NROWS   (NHOPS * NN)   // 150000
#define BINSH   9              // 512 rows per coarse bin
#define NBIN    293            // ceil(150016/512)
#define CAPB    12288          // per-bin region capacity (mean ~9.7k incl pad)
#define ABLK    1024           // binning blocks: 4/CU by LDS
#define DEPTH   32             // LDS circular buffer depth per bin
#define STG     6144           // fill2b per-half stage capacity (mean ~4096)
#define LSTR    136
#define SENT    0xFFFFFFFFu

typedef __bf16 bf16x8 __attribute__((ext_vector_type(8)));
typedef __bf16 bf16x4 __attribute__((ext_vector_type(4)));
typedef float  f32x4  __attribute__((ext_vector_type(4)));

__device__ __forceinline__ float silu_f(float v) { return v / (1.0f + expf(-v)); }

__device__ __forceinline__ f32x4 mm(bf16x8 a, bf16x8 b, f32x4 c) {
    return __builtin_amdgcn_mfma_f32_16x16x32_bf16(a, b, c, 0, 0, 0);
}

__device__ __forceinline__ float blo(unsigned v) { return __builtin_bit_cast(float, v << 16); }
__device__ __forceinline__ float bhi(unsigned v) { return __builtin_bit_cast(float, v & 0xffff0000u); }
__device__ __forceinline__ unsigned pk2(float a, float b) {
    unsigned short ua = __builtin_bit_cast(unsigned short, (__bf16)a);
    unsigned short ub = __builtin_bit_cast(unsigned short, (__bf16)b);
    return (unsigned)ua | ((unsigned)ub << 16);
}

// ---------------------------------------------------------------- fused weight pack + emb convert
__device__ __forceinline__ void packw_elem(
    const float* __restrict__ W, __bf16* __restrict__ out, int K, long idx)
{
    long per = (long)K * 128;
    long mat = idx / per, e = idx - mat * per;
    int j = (int)(e & 7), n16 = (int)((e >> 3) & 15), q = (int)((e >> 7) & 3),
        mt = (int)((e >> 9) & 7), kt = (int)(e >> 12);
    int k = kt * 32 + q * 8 + j, n = mt * 16 + n16;
    out[idx] = (__bf16)W[mat * per + (long)k * 128 + n];
}

__global__ __launch_bounds__(256) void k_packall(
    const float* __restrict__ projW, __bf16* __restrict__ pproj,
    const float* __restrict__ sInW,  __bf16* __restrict__ pin,
    const float* __restrict__ sSkW,  __bf16* __restrict__ psk,
    const float* __restrict__ mW1,   __bf16* __restrict__ pw1,
    const float* __restrict__ mW2,   __bf16* __restrict__ pw2,
    const float* __restrict__ Ea, const float* __restrict__ Eh,
    const float* __restrict__ Ed, const float* __restrict__ Ey,
    __bf16* __restrict__ embb)
{
    long tid = (long)blockIdx.x * 256 + threadIdx.x;
    if (tid < 32768) { packw_elem(projW, pproj, 256, tid); return; }
    tid -= 32768;
    if (tid < 196608) { packw_elem(sInW, pin, 512, tid); return; }
    tid -= 196608;
    if (tid < 196608) { packw_elem(sSkW, psk, 512, tid); return; }
    tid -= 196608;
    if (tid < 98304) { packw_elem(mW1, pw1, 128, tid); return; }
    tid -= 98304;
    if (tid < 98304) { packw_elem(mW2, pw2, 128, tid); return; }
    tid -= 98304;
    if (tid < 8000) {
        int t = (int)tid;
        float v;
        if (t < 6400) v = Ea[t];
        else if (t < 6976) v = Eh[t - 6400];
        else if (t < 7488) v = Ed[t - 6976];
        else v = Ey[t - 7488];
        embb[t] = (__bf16)v;
    }
}

// ---------------------------------------------------------------- K0: embed + project + silu (MFMA)
__global__ __launch_bounds__(256) void k_embed_m(
    const int* __restrict__ atom, const int* __restrict__ hc,
    const int* __restrict__ deg,  const int* __restrict__ hyb,
    const __bf16* __restrict__ emb, const __bf16* __restrict__ pw,
    const float* __restrict__ pb, __bf16* __restrict__ x)
{
    const int lane = threadIdx.x & 63, wid = threadIdx.x >> 6;
    const int q = lane >> 4, l16 = lane & 15;
    const int nb = blockIdx.x * 128 + wid * 32;
    int ia[2][4];
#pragma unroll
    for (int nt = 0; nt < 2; ++nt) {
        int n = nb + nt * 16 + l16;
        if (n >= NN) n = NN - 1;
        ia[nt][0] = atom[n]; ia[nt][1] = hc[n]; ia[nt][2] = deg[n]; ia[nt][3] = hyb[n];
    }
    f32x4 acc[2][8];
#pragma unroll
    for (int nt = 0; nt < 2; ++nt)
#pragma unroll
        for (int mt = 0; mt < 8; ++mt) acc[nt][mt] = (f32x4)(0.f);
    const int tb[4] = {0, 6400, 6976, 7488};
    for (int kt = 0; kt < 8; ++kt) {
        int t = kt >> 1;
        int koff = (kt & 1) * 32 + q * 8;
        bf16x8 bfrag[2];
#pragma unroll
        for (int nt = 0; nt < 2; ++nt)
            bfrag[nt] = *(const bf16x8*)(emb + tb[t] + (long)ia[nt][t] * 64 + koff);
        const __bf16* ap = pw + (long)kt * 4096 + lane * 8;
#pragma unroll
        for (int mt = 0; mt < 8; ++mt) {
            bf16x8 a = *(const bf16x8*)(ap + mt * 512);
            acc[0][mt] = mm(a, bfrag[0], acc[0][mt]);
            acc[1][mt] = mm(a, bfrag[1], acc[1][mt]);
        }
    }
#pragma unroll
    for (int nt = 0; nt < 2; ++nt) {
        long node = nb + nt * 16 + l16;
#pragma unroll
        for (int mt = 0; mt < 8; ++mt) {
            int ch = mt * 16 + q * 4;
            float4 bb = *(const float4*)(pb + ch);
            bf16x4 o;
            o[0] = (__bf16)silu_f(acc[nt][mt][0] + bb.x);
            o[1] = (__bf16)silu_f(acc[nt][mt][1] + bb.y);
            o[2] = (__bf16)silu_f(acc[nt][mt][2] + bb.z);
            o[3] = (__bf16)silu_f(acc[nt][mt][3] + bb.w);
            *(bf16x4*)(x + node * 128 + ch) = o;
        }
    }
}

// ---------------------------------------------------------------- CSR pass A: LDS write-combined binning
__global__ __launch_bounds__(256) void k_binA(
    const int* __restrict__ target, const int* __restrict__ src,
    int* __restrict__ gbincur, int* __restrict__ brealc,
    unsigned int* __restrict__ binreg)
{
    __shared__ unsigned int buf[NBIN][DEPTH];
    __shared__ int cnt[NBIN];
    __shared__ int flushed[NBIN];
    const int tid = threadIdx.x;
    for (int i = tid; i < NBIN; i += 256) { cnt[i] = 0; flushed[i] = 0; }
    __syncthreads();
    const int per = (NE + ABLK - 1) / ABLK;   // 2344
    const int e0 = blockIdx.x * per;
    const int e1 = (e0 + per < NE) ? e0 + per : NE;
    for (int base = e0; base < e1; base += 256) {
        int e = base + tid;
        if (e < e1) {
            int s = src[e];
            if (s >= 2 * NN) s -= 2 * NN; else if (s >= NN) s -= NN;
            int t = target[e];
            int bin = t >> BINSH;
            unsigned val = (unsigned)s | ((unsigned)(t & ((1 << BINSH) - 1)) << 16);
            int slot = atomicAdd(&cnt[bin], 1);
            buf[bin][slot & (DEPTH - 1)] = val;
        }
        __syncthreads();
        for (int b = tid; b < NBIN; b += 256) {
            while (cnt[b] - flushed[b] >= 16) {
                int pos = atomicAdd(&gbincur[b], 16);
                if (pos + 16 <= CAPB) {
                    uint4* d4 = (uint4*)(binreg + (long)b * CAPB + pos);
                    const uint4* s4 = (const uint4*)&buf[b][flushed[b] & (DEPTH - 1)];
                    d4[0] = s4[0]; d4[1] = s4[1]; d4[2] = s4[2]; d4[3] = s4[3];
                }
                flushed[b] += 16;
            }
        }
        __syncthreads();
    }
    for (int b = tid; b < NBIN; b += 256) {
        int lvl = cnt[b] - flushed[b];
        if (cnt[b] > 0) atomicAdd(&brealc[b], cnt[b]);
        if (lvl > 0) {
            int pad = (lvl + 3) & ~3;
            int pos = atomicAdd(&gbincur[b], pad);
            for (int i = 0; i < pad; i += 4) {
                uint4 v;
                v.x = (i + 0 < lvl) ? buf[b][(flushed[b] + i + 0) & (DEPTH - 1)] : SENT;
                v.y = (i + 1 < lvl) ? buf[b][(flushed[b] + i + 1) & (DEPTH - 1)] : SENT;
                v.z = (i + 2 < lvl) ? buf[b][(flushed[b] + i + 2) & (DEPTH - 1)] : SENT;
                v.w = (i + 3 < lvl) ? buf[b][(flushed[b] + i + 3) & (DEPTH - 1)] : SENT;
                if (pos + i + 4 <= CAPB)
                    *(uint4*)(binreg + (long)b * CAPB + pos + i) = v;
            }
        }
    }
}

// ---------------------------------------------------------------- CSR pass B: per-HALF-bin LDS finalize
__global__ __launch_bounds__(512) void k_fill2b(
    const unsigned int* __restrict__ binreg, const int* __restrict__ gbincur,
    const int* __restrict__ brealc, int* __restrict__ csr_start,
    unsigned short* __restrict__ esrc)
{
    __shared__ unsigned int stage[STG];
    __shared__ int pc[512], rcnt[256], scn[256], cur[256];
    __shared__ int nstage;
    const int blk = blockIdx.x;
    const int b = blk >> 1, half = blk & 1;
    const int tid = threadIdx.x;
    int pv = (tid < NBIN) ? brealc[tid] : 0;
    if (pv < 0) pv = 0;
    pc[tid] = pv;
    if (tid == 0) nstage = 0;
    if (tid < 256) rcnt[tid] = 0;
    __syncthreads();
    for (int off = 1; off < 512; off <<= 1) {
        int t = (tid >= off) ? pc[tid - off] : 0;
        __syncthreads();
        pc[tid] += t;
        __syncthreads();
    }
    const int bbase = (b == 0) ? 0 : pc[b - 1];
    const int breal = pc[b] - bbase;
    int total = gbincur[b];
    if (total > CAPB) total = CAPB;
    if (total < 0) total = 0;
    const unsigned int* seg = binreg + (long)b * CAPB;
    for (int i = tid; i < total; i += 512) {
        unsigned pk = seg[i];
        if (pk == SENT) continue;
        int tl = (pk >> 16) & 511;
        if ((tl >> 8) == half) {
            int p = atomicAdd(&nstage, 1);
            if (p < STG) stage[p] = pk;
            atomicAdd(&rcnt[tl & 255], 1);
        }
    }
    __syncthreads();
    int own = nstage; if (own > STG) own = STG;
    const int base0 = bbase + (half ? (breal - own) : 0);
    if (tid < 256) scn[tid] = rcnt[tid];
    __syncthreads();
    for (int off = 1; off < 256; off <<= 1) {
        int t = (tid >= off && tid < 256) ? scn[tid - off] : 0;
        __syncthreads();
        if (tid < 256) scn[tid] += t;
        __syncthreads();
    }
    if (tid < 256) {
        int v = rcnt[tid];
        int rb = base0 + scn[tid] - v;
        cur[tid] = rb;
        int row = b * 512 + half * 256 + tid;
        if (row <= NROWS) csr_start[row] = rb;
    }
    __syncthreads();
    for (int i = tid; i < own; i += 512) {
        unsigned pk = stage[i];
        int pos = atomicAdd(&cur[(pk >> 16) & 255], 1);
        if (pos >= 0 && pos < NE) esrc[pos] = (unsigned short)(pk & 0xffffu);
    }
}

// ---------------------------------------------------------------- K1: CSR gather, 4 rows/wave, uint4 loads
__global__ __launch_bounds__(256) void k_gather(
    const unsigned short* __restrict__ esrc, const int* __restrict__ csr_start,
    const uint4* __restrict__ x8, uint4* __restrict__ agg8)
{
    int row = blockIdx.x * 16 + (threadIdx.x >> 4);
    int lane = threadIdx.x & 63;
    int l4 = lane & 15, qw = lane >> 4;
    int e0 = csr_start[row], e1 = csr_start[row + 1];
    if ((unsigned)e0 > NE || (unsigned)e1 > NE || e1 < e0) { e0 = 0; e1 = 0; }
    int nch = (e1 - e0 + 15) >> 4;
    int n0 = __shfl(nch, 0, 64), n1 = __shfl(nch, 16, 64);
    int n2 = __shfl(nch, 32, 64), n3 = __shfl(nch, 48, 64);
    int nmax = max(max(n0, n1), max(n2, n3));
    float a0 = 0.f, a1 = 0.f, a2 = 0.f, a3 = 0.f, a4 = 0.f, a5 = 0.f, a6 = 0.f, a7 = 0.f;
    const int sb = qw << 4;
    for (int c = 0; c < nmax; ++c) {
        int base = e0 + c * 16;
        int rem = e1 - base;
        int pre = (l4 < rem) ? (int)esrc[base + l4] : 0;
        int m = rem < 16 ? (rem < 0 ? 0 : rem) : 16;
        int j = 0;
        for (; j + 3 < m; j += 4) {
            int sA = __shfl(pre, sb + j, 64);
            int sB = __shfl(pre, sb + j + 1, 64);
            int sC = __shfl(pre, sb + j + 2, 64);
            int sD = __shfl(pre, sb + j + 3, 64);
            uint4 v0 = x8[(long)sA * 16 + l4];
            uint4 v1 = x8[(long)sB * 16 + l4];
            uint4 v2 = x8[(long)sC * 16 + l4];
            uint4 v3 = x8[(long)sD * 16 + l4];
            a0 += blo(v0.x) + blo(v1.x) + blo(v2.x) + blo(v3.x);
            a1 += bhi(v0.x) + bhi(v1.x) + bhi(v2.x) + bhi(v3.x);
            a2 += blo(v0.y) + blo(v1.y) + blo(v2.y) + blo(v3.y);
            a3 += bhi(v0.y) + bhi(v1.y) + bhi(v2.y) + bhi(v3.y);
            a4 += blo(v0.z) + blo(v1.z) + blo(v2.z) + blo(v3.z);
            a5 += bhi(v0.z) + bhi(v1.z) + bhi(v2.z) + bhi(v3.z);
            a6 += blo(v0.w) + blo(v1.w) + blo(v2.w) + blo(v3.w);
            a7 += bhi(v0.w) + bhi(v1.w) + bhi(v2.w) + bhi(v3.w);
        }
        for (; j < m; ++j) {
            int sA = __shfl(pre, sb + j, 64);
            uint4 v0 = x8[(long)sA * 16 + l4];
            a0 += blo(v0.x); a1 += bhi(v0.x); a2 += blo(v0.y); a3 += bhi(v0.y);
            a4 += blo(v0.z); a5 += bhi(v0.z); a6 += blo(v0.w); a7 += bhi(v0.w);
        }
    }
    int hop = row / NN, node = row - hop * NN;
    uint4 o;
    o.x = pk2(a0, a1); o.y = pk2(a2, a3); o.z = pk2(a4, a5); o.w = pk2(a6, a7);
    agg8[((long)hop * NNP + node) * 16 + l4] = o;
}

// ---------------------------------------------------------------- K2: FUSED layer (R11: channel-half, single buffer)
__global__ __launch_bounds__(128) void k_layer(
    const __bf16* __restrict__ x, const __bf16* __restrict__ agg,
    const __bf16* __restrict__ pwin, const float* __restrict__ bin,
    const __bf16* __restrict__ pwsk, const float* __restrict__ bsk,
    const __bf16* __restrict__ pw1a, const float* __restrict__ b1a,
    const __bf16* __restrict__ pw2a, const float* __restrict__ b2a,
    const __bf16* __restrict__ pw1b, const float* __restrict__ b1b,
    const __bf16* __restrict__ pw2b, const float* __restrict__ b2b,
    __bf16* __restrict__ xout)
{
    __shared__ __bf16 L[16 * LSTR];
    const int lane = threadIdx.x & 63, half = threadIdx.x >> 6;
    const int q = lane >> 4, l16 = lane & 15;
    const int nb = blockIdx.x * 16;
    const int mtoff = half * 4 * 512;
    const int chb = half * 64;
    const int la = lane * 8;
    const long r0 = (long)(nb + l16) * 128;
    const __bf16* planes[4] = {x, agg, agg + (long)NNP * 128, agg + 2L * NNP * 128};

    // ---- shell phase: K=512, B-ring depth 8 ----
    bf16x8 ring[8];
#pragma unroll
    for (int k = 0; k < 8; ++k)
        ring[k] = *(const bf16x8*)(planes[k >> 2] + (k & 3) * 32 + q * 8 + r0);
    f32x4 aci[4], acs[4];
#pragma unroll
    for (int mt = 0; mt < 4; ++mt) { aci[mt] = (f32x4)(0.f); acs[mt] = (f32x4)(0.f); }
#pragma unroll
    for (int kt = 0; kt < 16; ++kt) {
        bf16x8 b0 = ring[kt & 7];
        if (kt < 8) {
            int k2 = kt + 8;
            ring[kt & 7] = *(const bf16x8*)(planes[k2 >> 2] + (k2 & 3) * 32 + q * 8 + r0);
        }
        const __bf16* aip = pwin + (long)kt * 4096 + mtoff + la;
        const __bf16* asp = pwsk + (long)kt * 4096 + mtoff + la;
#pragma unroll
        for (int mt = 0; mt < 4; ++mt) {
            aci[mt] = mm(*(const bf16x8*)(aip + mt * 512), b0, aci[mt]);
            acs[mt] = mm(*(const bf16x8*)(asp + mt * 512), b0, acs[mt]);
        }
    }
    bf16x4 gk[4];
    bf16x4 hs[4];
#pragma unroll
    for (int mt = 0; mt < 4; ++mt) {
        int ch = chb + mt * 16 + q * 4;
        float4 bi = *(const float4*)(bin + ch);
        float4 bs = *(const float4*)(bsk + ch);
        bf16x4 oh, og;
        oh[0] = (__bf16)silu_f(aci[mt][0] + bi.x);
        oh[1] = (__bf16)silu_f(aci[mt][1] + bi.y);
        oh[2] = (__bf16)silu_f(aci[mt][2] + bi.z);
        oh[3] = (__bf16)silu_f(aci[mt][3] + bi.w);
        og[0] = (__bf16)(acs[mt][0] + bs.x);
        og[1] = (__bf16)(acs[mt][1] + bs.y);
        og[2] = (__bf16)(acs[mt][2] + bs.z);
        og[3] = (__bf16)(acs[mt][3] + bs.w);
        hs[mt] = oh; gk[mt] = og;
        *(bf16x4*)(L + l16 * LSTR + ch) = oh;
    }
    __syncthreads();

    f32x4 acc[4];
    bf16x4 skipreg[4];

    // ---- p0: t1 = silu(h @ W1a + b1a) -> LDS ----
#pragma unroll
    for (int mt = 0; mt < 4; ++mt) acc[mt] = (f32x4)(0.f);
#pragma unroll
    for (int kt = 0; kt < 4; ++kt) {
        int koff = kt * 32 + q * 8;
        bf16x8 f0 = *(const bf16x8*)(L + l16 * LSTR + koff);
        const __bf16* ap = pw1a + (long)kt * 4096 + mtoff + la;
#pragma unroll
        for (int mt = 0; mt < 4; ++mt)
            acc[mt] = mm(*(const bf16x8*)(ap + mt * 512), f0, acc[mt]);
    }
    __syncthreads();
#pragma unroll
    for (int mt = 0; mt < 4; ++mt) {
        int ch = chb + mt * 16 + q * 4;
        float4 bb = *(const float4*)(b1a + ch);
        bf16x4 o;
        o[0] = (__bf16)silu_f(acc[mt][0] + bb.x);
        o[1] = (__bf16)silu_f(acc[mt][1] + bb.y);
        o[2] = (__bf16)silu_f(acc[mt][2] + bb.z);
        o[3] = (__bf16)silu_f(acc[mt][3] + bb.w);
        *(bf16x4*)(L + l16 * LSTR + ch) = o;
    }
    __syncthreads();

    // ---- p1: h2 = t1 @ W2a + b2a + h -> LDS + skipreg ----
#pragma unroll
    for (int mt = 0; mt < 4; ++mt) acc[mt] = (f32x4)(0.f);
#pragma unroll
    for (int kt = 0; kt < 4; ++kt) {
        int koff = kt * 32 + q * 8;
        bf16x8 f0 = *(const bf16x8*)(L + l16 * LSTR + koff);
        const __bf16* ap = pw2a + (long)kt * 4096 + mtoff + la;
#pragma unroll
        for (int mt = 0; mt < 4; ++mt)
            acc[mt] = mm(*(const bf16x8*)(ap + mt * 512), f0, acc[mt]);
    }
    __syncthreads();
#pragma unroll
    for (int mt = 0; mt < 4; ++mt) {
        int ch = chb + mt * 16 + q * 4;
        float4 bb = *(const float4*)(b2a + ch);
        bf16x4 sk = hs[mt];
        bf16x4 o;
        o[0] = (__bf16)(acc[mt][0] + bb.x + (float)sk[0]);
        o[1] = (__bf16)(acc[mt][1] + bb.y + (float)sk[1]);
        o[2] = (__bf16)(acc[mt][2] + bb.z + (float)sk[2]);
        o[3] = (__bf16)(acc[mt][3] + bb.w + (float)sk[3]);
        skipreg[mt] = o;
        *(bf16x4*)(L + l16 * LSTR + ch) = o;
    }
    __syncthreads();

    // ---- p2: t2 = silu(h2 @ W1b + b1b) -> LDS ----
#pragma unroll
    for (int mt = 0; mt < 4; ++mt) acc[mt] = (f32x4)(0.f);
#pragma unroll
    for (int kt = 0; kt < 4; ++kt) {
        int koff = kt * 32 + q * 8;
        bf16x8 f0 = *(const bf16x8*)(L + l16 * LSTR + koff);
        const __bf16* ap = pw1b + (long)kt * 4096 + mtoff + la;
#pragma unroll
        for (int mt = 0; mt < 4; ++mt)
            acc[mt] = mm(*(const bf16x8*)(ap + mt * 512), f0, acc[mt]);
    }
    __syncthreads();
#pragma unroll
    for (int mt = 0; mt < 4; ++mt) {
        int ch = chb + mt * 16 + q * 4;
        float4 bb = *(const float4*)(b1b + ch);
        bf16x4 o;
        o[0] = (__bf16)silu_f(acc[mt][0] + bb.x);
        o[1] = (__bf16)silu_f(acc[mt][1] + bb.y);
        o[2] = (__bf16)silu_f(acc[mt][2] + bb.z);
        o[3] = (__bf16)silu_f(acc[mt][3] + bb.w);
        *(bf16x4*)(L + l16 * LSTR + ch) = o;
    }
    __syncthreads();

    // ---- p3: x = t2 @ W2b + b2b + h2 + gskip -> global ----
#pragma unroll
    for (int mt = 0; mt < 4; ++mt) acc[mt] = (f32x4)(0.f);
#pragma unroll
    for (int kt = 0; kt < 4; ++kt) {
        int koff = kt * 32 + q * 8;
        bf16x8 f0 = *(const bf16x8*)(L + l16 * LSTR + koff);
        const __bf16* ap = pw2b + (long)kt * 4096 + mtoff + la;
#pragma unroll
        for (int mt = 0; mt < 4; ++mt)
            acc[mt] = mm(*(const bf16x8*)(ap + mt * 512), f0, acc[mt]);
    }
    long node = nb + l16;
#pragma unroll
    for (int mt = 0; mt < 4; ++mt) {
        int ch = chb + mt * 16 + q * 4;
        float4 bb = *(const float4*)(b2b + ch);
        bf16x4 sk = skipreg[mt];
        bf16x4 g = gk[mt];
        bf16x4 o;
        o[0] = (__bf16)(acc[mt][0] + bb.x + (float)sk[0] + (float)g[0]);
        o[1] = (__bf16)(acc[mt][1] + bb.y + (float)sk[1] + (float)g[1]);
        o[2] = (__bf16)(acc[mt][2] + bb.z + (float)sk[2] + (float)g[2]);
        o[3] = (__bf16)(acc[mt][3] + bb.w + (float)sk[3] + (float)g[3]);
        *(bf16x4*)(xout + node * 128 + ch) = o;
    }
}

// ---------------------------------------------------------------- K4: attention scores
__global__ __launch_bounds__(256) void k_scores(
    const __bf16* __restrict__ x, const float* __restrict__ aw,
    const float* __restrict__ ab, const float* __restrict__ temp,
    float* __restrict__ scores)
{
    int wave = threadIdx.x >> 6, lane = threadIdx.x & 63;
    int n = blockIdx.x * 4 + wave;
    if (n >= NN) return;
    float x0 = (float)x[(long)n * H + lane];
    float x1 = (float)x[(long)n * H + 64 + lane];
    float T = temp[0];
#pragma unroll
    for (int hh = 0; hh < NHEADS; ++hh) {
        float p = x0 * aw[hh * H + lane] + x1 * aw[hh * H + 64 + lane];
#pragma unroll
        for (int off = 32; off >= 1; off >>= 1) p += __shfl_xor(p, off, 64);
        if (lane == 0) scores[n * NHEADS + hh] = (p + ab[hh]) / T;
    }
}

// ---------------------------------------------------------------- K5: graph offsets
__global__ __launch_bounds__(256) void k_offsets(
    const int* __restrict__ batch, int* __restrict__ gstart)
{
    int n = blockIdx.x * 256 + threadIdx.x;
    if (n >= NN) return;
    int b = batch[n];
    int bp = (n == 0) ? -1 : batch[n - 1];
    for (int g = bp + 1; g <= b; ++g) gstart[g] = n;
    if (n == NN - 1) for (int g = b + 1; g <= NG; ++g) gstart[g] = NN;
}

// ---------------------------------------------------------------- K6: softmax pool
__global__ __launch_bounds__(64) void k_pool(
    const __bf16* __restrict__ x, const float* __restrict__ scores,
    const int* __restrict__ gstart, float* __restrict__ pooled)
{
    int g = blockIdx.x, lane = threadIdx.x;
    int s0 = gstart[g], s1 = gstart[g + 1];
    float m0 = -INFINITY, m1 = -INFINITY, m2 = -INFINITY, m3 = -INFINITY;
    for (int n = s0 + lane; n < s1; n += 64) {
        m0 = fmaxf(m0, scores[n * 4 + 0]); m1 = fmaxf(m1, scores[n * 4 + 1]);
        m2 = fmaxf(m2, scores[n * 4 + 2]); m3 = fmaxf(m3, scores[n * 4 + 3]);
    }
#pragma unroll
    for (int off = 32; off >= 1; off >>= 1) {
        m0 = fmaxf(m0, __shfl_xor(m0, off, 64)); m1 = fmaxf(m1, __shfl_xor(m1, off, 64));
        m2 = fmaxf(m2, __shfl_xor(m2, off, 64)); m3 = fmaxf(m3, __shfl_xor(m3, off, 64));
    }
    float d0 = 0.f, d1 = 0.f, d2 = 0.f, d3 = 0.f;
    for (int n = s0 + lane; n < s1; n += 64) {
        d0 += expf(scores[n * 4 + 0] - m0); d1 += expf(scores[n * 4 + 1] - m1);
        d2 += expf(scores[n * 4 + 2] - m2); d3 += expf(scores[n * 4 + 3] - m3);
    }
#pragma unroll
    for (int off = 32; off >= 1; off >>= 1) {
        d0 += __shfl_xor(d0, off, 64); d1 += __shfl_xor(d1, off, 64);
        d2 += __shfl_xor(d2, off, 64); d3 += __shfl_xor(d3, off, 64);
    }
    float i0 = d0 > 0.f ? 1.f / d0 : 0.f;
    float i1 = d1 > 0.f ? 1.f / d1 : 0.f;
    float i2 = d2 > 0.f ? 1.f / d2 : 0.f;
    float i3 = d3 > 0.f ? 1.f / d3 : 0.f;
    float a0 = 0.f, a1 = 0.f;
    for (int n = s0; n < s1; ++n) {
        float wb = expf(scores[n * 4 + 0] - m0) * i0 + expf(scores[n * 4 + 1] - m1) * i1
                 + expf(scores[n * 4 + 2] - m2) * i2 + expf(scores[n * 4 + 3] - m3) * i3;
        wb *= 0.25f;
        a0 += wb * (float)x[(long)n * H + lane];
        a1 += wb * (float)x[(long)n * H + 64 + lane];
    }
    pooled[g * H + lane] = a0;
    pooled[g * H + 64 + lane] = a1;
}

// ---------------------------------------------------------------- K7: FFN readout
__global__ __launch_bounds__(128) void k_ffn(
    const float* __restrict__ pooled,
    const float* __restrict__ W1, const float* __restrict__ B1,
    const float* __restrict__ W2, const float* __restrict__ B2,
    const float* __restrict__ W3, const float* __restrict__ B3,
    float* __restrict__ out)
{
    __shared__ float p[H], t1[H], t2[H], red[H];
    int g = blockIdx.x, c = threadIdx.x;
    p[c] = pooled[g * H + c];
    __syncthreads();
    float acc = 0.f;
    for (int k = 0; k < H; ++k) acc += p[k] * W1[k * H + c];
    t1[c] = silu_f(acc + B1[c]);
    __syncthreads();
    acc = 0.f;
    for (int k = 0; k < H; ++k) acc += t1[k] * W2[k * H + c];
    t2[c] = silu_f(acc + B2[c]);
    __syncthreads();
    red[c] = t2[c] * W3[c];
    __syncthreads();
    for (int off = 64; off >= 1; off >>= 1) {
        if (c < off) red[c] += red[c + off];
        __syncthreads();
    }
    if (c == 0) out[g] = red[0] + B3[0];
}

// ---------------------------------------------------------------- launch
extern "C" void kernel_launch(void* const* d_in, const int* in_sizes, int n_in,
                              void* d_out, int out_size, void* d_ws, size_t ws_size,
                              hipStream_t stream)
{
    const int*   atom   = (const int*)d_in[0];
    const int*   hc     = (const int*)d_in[1];
    const int*   deg    = (const int*)d_in[2];
    const int*   hyb    = (const int*)d_in[3];
    const int*   target = (const int*)d_in[4];
    const int*   src    = (const int*)d_in[5];
    const int*   batch  = (const int*)d_in[6];
    const float* Ea     = (const float*)d_in[7];
    const float* Eh     = (const float*)d_in[8];
    const float* Ed     = (const float*)d_in[9];
    const float* Ey     = (const float*)d_in[10];
    const float* projW  = (const float*)d_in[11];
    const float* projB  = (const float*)d_in[12];
    const float* sInW   = (const float*)d_in[13];
    const float* sInB   = (const float*)d_in[14];
    const float* mW1    = (const float*)d_in[15];
    const float* mB1    = (const float*)d_in[16];
    const float* mW2    = (const float*)d_in[17];
    const float* mB2    = (const float*)d_in[18];
    const float* sSkW   = (const float*)d_in[19];
    const float* sSkB   = (const float*)d_in[20];
    const float* attnW  = (const float*)d_in[21];
    const float* attnB  = (const float*)d_in[22];
    const float* temp   = (const float*)d_in[23];
    const float* fW1    = (const float*)d_in[24];
    const float* fB1    = (const float*)d_in[25];
    const float* fW2    = (const float*)d_in[26];
    const float* fB2    = (const float*)d_in[27];
    const float* fW3    = (const float*)d_in[28];
    const float* fB3    = (const float*)d_in[29];
    float* out = (float*)d_out;

    char* w = (char*)d_ws;
    auto take = [&](size_t bytes) { void* p = (void*)w; w += (bytes + 255) & ~(size_t)255; return p; };
    __bf16* x      = (__bf16*)take(2L * NNP * H);
    __bf16* agg    = (__bf16*)take(2L * 3 * NNP * H);
    __bf16* pproj  = (__bf16*)take(2L * 256 * H);
    __bf16* pin    = (__bf16*)take(2L * 3 * 512 * H);
    __bf16* psk    = (__bf16*)take(2L * 3 * 512 * H);
    __bf16* pw1    = (__bf16*)take(2L * 6 * 128 * H);
    __bf16* pw2    = (__bf16*)take(2L * 6 * 128 * H);
    __bf16* embb   = (__bf16*)take(2L * 8000);
    float*  scores = (float*)take(4L * NN * NHEADS);
    float*  pooled = (float*)take(4L * NG * H);
    int*    gstart = (int*)take(4L * (NG + 1));
    int*    csr_start = (int*)take(4L * (NROWS + 1));
    unsigned int*   binreg = (unsigned int*)take(4L * NBIN * CAPB);   // 14.4 MB
    unsigned short* esrc   = (unsigned short*)take(2L * NE);
    int*    gbincur = (int*)take(4L * 2 * NBIN);
    int*    brealc  = gbincur + NBIN;

    // ---- fused weight pack + emb convert (weights restored each call) ----
    k_packall<<<(630592 + 255) / 256, 256, 0, stream>>>(
        projW, pproj, sInW, pin, sSkW, psk, mW1, pw1, mW2, pw2,
        Ea, Eh, Ed, Ey, embb);

    // ---- CSR build: write-combined binning -> per-half-bin finalize ----
    hipMemsetAsync(gbincur, 0, sizeof(int) * 2 * NBIN, stream);
    k_binA<<<ABLK, 256, 0, stream>>>(target, src, gbincur, brealc, binreg);
    k_fill2b<<<2 * NBIN, 512, 0, stream>>>(binreg, gbincur, brealc, csr_start, esrc);

    k_embed_m<<<NNP / 128, 256, 0, stream>>>(atom, hc, deg, hyb, embb, pproj, projB, x);
    k_offsets<<<(NN + 255) / 256, 256, 0, stream>>>(batch, gstart);

    for (int l = 0; l < NL; ++l) {
        k_gather<<<NROWS / 16, 256, 0, stream>>>(esrc, csr_start,
            (const uint4*)x, (uint4*)agg);
        k_layer<<<NNP / 16, 128, 0, stream>>>(x, agg,
            pin + (long)l * 512 * H, sInB + l * H,
            psk + (long)l * 512 * H, sSkB + l * H,
            pw1 + (long)(l * NMLP + 0) * 128 * H, mB1 + (long)(l * NMLP + 0) * H,
            pw2 + (long)(l * NMLP + 0) * 128 * H, mB2 + (long)(l * NMLP + 0) * H,
            pw1 + (long)(l * NMLP + 1) * 128 * H, mB1 + (long)(l * NMLP + 1) * H,
            pw2 + (long)(l * NMLP + 1) * 128 * H, mB2 + (long)(l * NMLP + 1) * H,
            x);
    }

    k_scores<<<NN / 4, 256, 0, stream>>>(x, attnW, attnB, temp, scores);
    k_pool<<<NG, 64, 0, stream>>>(x, scores, gstart, pooled);
    k_ffn<<<NG, 128, 0, stream>>>(pooled, fW1, fB1, fW2, fB2, fW3, fB3, out);
}